// Round 4
// baseline (795.584 us; speedup 1.0000x reference)
//
#include <hip/hip_runtime.h>

#define NPT 100
#define KK 10

typedef __attribute__((ext_vector_type(8))) short short8;
typedef __attribute__((ext_vector_type(4))) float float4v;

__device__ __forceinline__ float leaky(float v){ return fmaxf(v, 0.2f*v); }
__device__ __forceinline__ unsigned short bf16r(float x){
  unsigned u = __float_as_uint(x);
  return (unsigned short)((u + 0x7FFFu + ((u>>16)&1u)) >> 16);
}
__device__ __forceinline__ float bf2f(unsigned short h){ return __uint_as_float(((unsigned)h)<<16); }

// d_ws layout. float offsets:
#define WV(w) (1024*(w))        // 9 folded 32x32 fp32 mats: W0f,Wp1,Wq1,W2f,Wp3,Wq3,W4f,Wp5,Wq5
#define W7G_OFF 9216            // W7 g-part folded fp32 [128][512]
// byte offsets:
#define W6B_OFF   299008        // W6 folded bf16 [512][288]  (K-blocks: 0-2 hi,3-5 hi,6-8 lo)
#define W796B_OFF 593920        // W7 96-part folded bf16 [128][288]
#define W8B_OFF   667648        // W8 folded bf16 [32][384]   (0-3 hi,4-7 hi,8-11 lo)

struct PrepP {
  const float* W[9];
  const float* s[9];
  float* ws;
};

__global__ __launch_bounds__(256) void prep_kernel(PrepP p){
  int gid = blockIdx.x*256 + threadIdx.x;
  int gs = gridDim.x*256;
  float* ws = p.ws;
  unsigned short* w6b  = (unsigned short*)((char*)ws + W6B_OFF);
  unsigned short* w796 = (unsigned short*)((char*)ws + W796B_OFF);
  unsigned short* w8b  = (unsigned short*)((char*)ws + W8B_OFF);
  // seg0: 9 folded vector mats [32][32]
  for(int i = gid; i < 9216; i += gs){
    int w = i >> 10, r = i & 1023, o = r >> 5, c = r & 31;
    float v = 0.f;
    switch(w){
      case 0: v = (c < 30) ? p.s[0][o]*p.W[0][o*30 + c] : 0.f; break;
      case 1: v = p.s[1][o]*p.W[1][o*64 + c]; break;
      case 2: v = p.s[1][o]*(p.W[1][o*64 + 32 + c] - p.W[1][o*64 + c]); break;
      case 3: v = p.s[2][o]*p.W[2][o*32 + c]; break;
      case 4: v = p.s[3][o]*p.W[3][o*64 + c]; break;
      case 5: v = p.s[3][o]*(p.W[3][o*64 + 32 + c] - p.W[3][o*64 + c]); break;
      case 6: v = p.s[4][o]*p.W[4][o*32 + c]; break;
      case 7: v = p.s[5][o]*p.W[5][o*64 + c]; break;
      case 8: v = p.s[5][o]*(p.W[5][o*64 + 32 + c] - p.W[5][o*64 + c]); break;
    }
    ws[i] = v;
  }
  // seg1: W7 g-part fp32 folded [128][512]
  for(int i = gid; i < 65536; i += gs){
    int o = i >> 9, c = i & 511;
    ws[W7G_OFF + i] = p.s[7][o]*p.W[7][o*608 + c];
  }
  // seg2: W6 bf16 [512][288]
  for(int i = gid; i < 147456; i += gs){
    int o = i/288, cc = i - o*288, kb = cc >> 5, k = cc & 31;
    int sc = (kb % 3)*32 + k;
    float w = p.s[6][o]*p.W[6][o*96 + sc];
    unsigned short h = bf16r(w);
    w6b[i] = (kb < 6) ? h : bf16r(w - bf2f(h));
  }
  // seg3: W7 96-part bf16 [128][288]
  for(int i = gid; i < 36864; i += gs){
    int o = i/288, cc = i - o*288, kb = cc >> 5, k = cc & 31;
    int sc = 512 + (kb % 3)*32 + k;
    float w = p.s[7][o]*p.W[7][o*608 + sc];
    unsigned short h = bf16r(w);
    w796[i] = (kb < 6) ? h : bf16r(w - bf2f(h));
  }
  // seg4: W8 bf16 [32][384]
  for(int i = gid; i < 12288; i += gs){
    int o = i/384, cc = i - o*384, kb = cc >> 5, k = cc & 31;
    int sc = (kb & 3)*32 + k;
    float w = p.s[8][o]*p.W[8][o*128 + sc];
    unsigned short h = bf16r(w);
    w8b[i] = (kb < 8) ? h : bf16r(w - bf2f(h));
  }
}

__device__ __forceinline__ void load32(const float* src, float* xr){
  #pragma unroll
  for(int q = 0; q < 8; ++q){
    float4v v = *(const float4v*)&src[q*4];
    xr[q*4+0] = v.x; xr[q*4+1] = v.y; xr[q*4+2] = v.z; xr[q*4+3] = v.w;
  }
}
__device__ __forceinline__ float dot32(const float* wrow, const float* xr){
  float a0 = 0.f, a1 = 0.f, a2 = 0.f, a3 = 0.f;
  #pragma unroll
  for(int q = 0; q < 8; ++q){
    float4v w = *(const float4v*)&wrow[q*4];
    a0 = fmaf(w.x, xr[q*4+0], a0);
    a1 = fmaf(w.y, xr[q*4+1], a1);
    a2 = fmaf(w.z, xr[q*4+2], a2);
    a3 = fmaf(w.w, xr[q*4+3], a3);
  }
  return (a0+a1)+(a2+a3);
}
// build hi/lo bf16 fragments (8 elems) from 8 consecutive fp32
__device__ __forceinline__ void buildB(const float* src, short8* bh, short8* bl){
  float4v v0 = *(const float4v*)&src[0];
  float4v v1 = *(const float4v*)&src[4];
  float xv[8] = {v0.x, v0.y, v0.z, v0.w, v1.x, v1.y, v1.z, v1.w};
  short8 h, l;
  #pragma unroll
  for(int j = 0; j < 8; ++j){
    unsigned short hh = bf16r(xv[j]);
    h[j] = (short)hh;
    l[j] = (short)bf16r(xv[j] - bf2f(hh));
  }
  *bh = h; *bl = l;
}

// conv2 k-chunk of 2: E in regs, weights broadcast from LDS
__device__ __forceinline__ void conv2_chunk2(int n, int k0, int ob,
    const unsigned char* IDXB, const float* PREG, const float* qt,
    const float* WST, float* acc){
  float e0[32], e1[32];
  const int j0 = IDXB[n*KK + k0];
  const int j1 = IDXB[n*KK + k0 + 1];
  #pragma unroll
  for(int q = 0; q < 8; ++q){
    float4v p0 = *(const float4v*)&PREG[j0*36 + q*4];
    float4v p1 = *(const float4v*)&PREG[j1*36 + q*4];
    e0[q*4+0] = leaky(p0.x + qt[q*4+0]);
    e0[q*4+1] = leaky(p0.y + qt[q*4+1]);
    e0[q*4+2] = leaky(p0.z + qt[q*4+2]);
    e0[q*4+3] = leaky(p0.w + qt[q*4+3]);
    e1[q*4+0] = leaky(p1.x + qt[q*4+0]);
    e1[q*4+1] = leaky(p1.y + qt[q*4+1]);
    e1[q*4+2] = leaky(p1.z + qt[q*4+2]);
    e1[q*4+3] = leaky(p1.w + qt[q*4+3]);
  }
  #pragma unroll
  for(int o = 0; o < 8; ++o){
    float d0a = 0.f, d0b = 0.f, d1a = 0.f, d1b = 0.f;
    #pragma unroll
    for(int q = 0; q < 8; ++q){
      float4v w = *(const float4v*)&WST[(ob + o)*32 + q*4];
      d0a = fmaf(w.x, e0[q*4+0], d0a); d0b = fmaf(w.y, e0[q*4+1], d0b);
      d0a = fmaf(w.z, e0[q*4+2], d0a); d0b = fmaf(w.w, e0[q*4+3], d0b);
      d1a = fmaf(w.x, e1[q*4+0], d1a); d1b = fmaf(w.y, e1[q*4+1], d1b);
      d1a = fmaf(w.z, e1[q*4+2], d1a); d1b = fmaf(w.w, e1[q*4+3], d1b);
    }
    acc[o] = fmaxf(acc[o], fmaxf(d0a + d0b, d1a + d1b));
  }
}

struct MainP {
  const float* obs;
  const float* W9;
  const float* t[9];
  const float* ws;
  float* out;
};

// 256 threads, 2 blocks/CU (LDS-limited). Verified-best structure.
// DO NOT raise block size to 512 (R1/R2: spills or 1-block residency, ~1.9x dur).
// RULE #20 FIX (this round): gmax[8] was indexed by the induction var of
// `#pragma unroll 1` loops -> local memory -> ~229 KB/block scratch writes
// (matches measured WRITE_SIZE ~264 KB/block). Fully unroll the mt loops so
// every gmax index is compile-time -> gmax lives in 32 VGPRs.
__global__ __launch_bounds__(256, 2) void dgcnn(MainP p){
  const int b = blockIdx.x;
  const int tid = threadIdx.x;
  const int lane = tid & 63, wv = tid >> 6;
  const int quad = lane >> 4, l15 = lane & 15;

  // LDS: 40000 + 14400 + 8192 + 400 + 128 + 1000 = 64120 B
  __shared__ __align__(16) float XBIG[10000];  // [100][100]: x1(0-31)|x2(32-63)|x3/x0/Q(64-95)|pad
  __shared__ __align__(16) float PREG[3600];   // obs stage -> P[100][36] -> h2[16][132]
  __shared__ __align__(16) float WST[2048];    // weight stage / g[512]+Rg[128]
  __shared__ __align__(16) float XX[100];
  __shared__ __align__(16) float TMP[32];
  __shared__ unsigned char IDXB[1000];

  const float* ws = p.ws;
  const unsigned short* w6b  = (const unsigned short*)((const char*)ws + W6B_OFF);
  const unsigned short* w796 = (const unsigned short*)((const char*)ws + W796B_OFF);
  const unsigned short* w8b  = (const unsigned short*)((const char*)ws + W8B_OFF);

  // ---- stage obs (zero-padded [100][36]) + W0f ----
  for(int i = tid; i < 3600; i += 256){
    int n = i/36, c = i - n*36;
    PREG[i] = (c < 30) ? p.obs[(size_t)b*3000 + n*30 + c] : 0.f;
  }
  for(int i = tid; i < 1024; i += 256) WST[i] = ws[WV(0) + i];
  __syncthreads();

  // ---- conv0 (vector fp32, folded s0) -> x0 at cols 64-95 ----
  if(tid < NPT){
    float xr[32]; load32(&PREG[tid*36], xr);
    #pragma unroll
    for(int ob = 0; ob < 8; ++ob){
      float4v y;
      #pragma unroll
      for(int oi = 0; oi < 4; ++oi){
        int o = ob*4 + oi;
        y[oi] = leaky(dot32(&WST[o*32], xr) + p.t[0][o]);
      }
      *(float4v*)&XBIG[tid*100 + 64 + ob*4] = y;
    }
  }
  __syncthreads();

  // ---- 3 edge layers ----
  const int XINs[3]  = {64, 0, 32};
  const int QOFFs[3] = {32, 64, 0};
  const int OUTs[3]  = {0, 32, 64};
  const int WPI[3]   = {1, 4, 7};

  for(int L = 0; L < 3; ++L){
    const int XIN = XINs[L], OUT = OUTs[L], QOFF = QOFFs[L];
    // stage Wp, Wq
    for(int i = tid; i < 1024; i += 256){
      WST[i]        = ws[WV(WPI[L])   + i];
      WST[1024 + i] = ws[WV(WPI[L]+1) + i];
    }
    __syncthreads();
    // xx
    if(tid < NPT){
      float xr[32]; load32(&XBIG[tid*100 + XIN], xr);
      float a = 0.f;
      #pragma unroll
      for(int c = 0; c < 32; ++c) a = fmaf(xr[c], xr[c], a);
      XX[tid] = a;
    }
    __syncthreads();
    // knn (waves 0-1) || P,Q GEMMs (waves 2-3)
    if(tid < 128){
      if(tid < NPT){
        const int n = tid;
        float xr[32]; load32(&XBIG[n*100 + XIN], xr);
        const float xxn = XX[n];
        float bv[KK]; int bj[KK];
        #pragma unroll
        for(int k = 0; k < KK; ++k){ bv[k] = -3.4e38f; bj[k] = 0; }
        #pragma unroll 1
        for(int m = 0; m < NPT; ++m){
          const float* xm = &XBIG[m*100 + XIN];
          float a0 = 0.f, a1 = 0.f, a2 = 0.f, a3 = 0.f;
          #pragma unroll
          for(int q = 0; q < 8; ++q){
            float4v v = *(const float4v*)&xm[q*4];
            a0 = fmaf(xr[q*4+0], v.x, a0);
            a1 = fmaf(xr[q*4+1], v.y, a1);
            a2 = fmaf(xr[q*4+2], v.z, a2);
            a3 = fmaf(xr[q*4+3], v.w, a3);
          }
          float d = 2.0f*((a0+a1)+(a2+a3)) - xxn - XX[m];
          if(d > bv[KK-1]){   // strict >: earlier m wins ties (matches lax.top_k)
            float cv = d; int ci = m;
            #pragma unroll
            for(int jj = 0; jj < KK; ++jj){
              bool sw = cv > bv[jj];
              float tv = bv[jj]; int ti = bj[jj];
              bv[jj] = sw ? cv : tv; bj[jj] = sw ? ci : ti;
              cv = sw ? tv : cv;    ci = sw ? ti : ci;
            }
          }
        }
        #pragma unroll
        for(int k = 0; k < KK; ++k) IDXB[n*KK + k] = (unsigned char)bj[k];
      }
    } else {
      int j = tid - 128;
      if(j < NPT){
        float xr[32]; load32(&XBIG[j*100 + XIN], xr);
        #pragma unroll 1
        for(int o = 0; o < 32; ++o) PREG[j*36 + o] = dot32(&WST[o*32], xr);
        if(L < 2){
          #pragma unroll 1
          for(int o = 0; o < 32; ++o) XBIG[j*100 + QOFF + o] = dot32(&WST[1024 + o*32], xr);
        }
      }
    }
    __syncthreads();

    if(L < 2){
      // stage conv weights (folded) + t-biases
      int wci = (L == 0) ? 3 : 6;
      for(int i = tid; i < 1024; i += 256) WST[i] = ws[WV(wci) + i];
      if(tid < 32){
        WST[1024 + tid] = p.t[1 + 2*L][tid];
        WST[1056 + tid] = p.t[2 + 2*L][tid];
      }
      __syncthreads();
      // conv2: thread = (n, o-octet); E regenerated per octet, weights LDS broadcast
      for(int it = tid; it < 400; it += 256){
        int n = it % 100, oct = it / 100, ob = oct*8;
        float qt[32];
        #pragma unroll
        for(int q = 0; q < 8; ++q){
          float4v qv = *(const float4v*)&XBIG[n*100 + QOFF + q*4];
          float4v tv = *(const float4v*)&WST[1024 + q*4];
          qt[q*4+0] = qv.x + tv.x; qt[q*4+1] = qv.y + tv.y;
          qt[q*4+2] = qv.z + tv.z; qt[q*4+3] = qv.w + tv.w;
        }
        float acc[8];
        #pragma unroll
        for(int o = 0; o < 8; ++o) acc[o] = -3.4e38f;
        conv2_chunk2(n, 0, ob, IDXB, PREG, qt, WST, acc);
        conv2_chunk2(n, 2, ob, IDXB, PREG, qt, WST, acc);
        conv2_chunk2(n, 4, ob, IDXB, PREG, qt, WST, acc);
        conv2_chunk2(n, 6, ob, IDXB, PREG, qt, WST, acc);
        conv2_chunk2(n, 8, ob, IDXB, PREG, qt, WST, acc);
        #pragma unroll
        for(int oh = 0; oh < 2; ++oh){
          float4v y;
          #pragma unroll
          for(int oi = 0; oi < 4; ++oi){
            int o = ob + oh*4 + oi;
            y[oi] = leaky(acc[oh*4 + oi] + WST[1056 + o]);
          }
          *(float4v*)&XBIG[n*100 + OUT + ob + oh*4] = y;
        }
      }
      __syncthreads();
    } else {
      // layer 3: x3 = leaky(max_k P[j] + Q + t5), Q computed in-reg
      if(tid < NPT){
        float xr[32]; load32(&XBIG[tid*100 + XIN], xr);
        float pm[32];
        #pragma unroll
        for(int o = 0; o < 32; ++o) pm[o] = -3.4e38f;
        #pragma unroll 1
        for(int k = 0; k < KK; ++k){
          int j = IDXB[tid*KK + k];
          #pragma unroll
          for(int q = 0; q < 8; ++q){
            float4v pv = *(const float4v*)&PREG[j*36 + q*4];
            pm[q*4+0] = fmaxf(pm[q*4+0], pv.x);
            pm[q*4+1] = fmaxf(pm[q*4+1], pv.y);
            pm[q*4+2] = fmaxf(pm[q*4+2], pv.z);
            pm[q*4+3] = fmaxf(pm[q*4+3], pv.w);
          }
        }
        #pragma unroll 1
        for(int o = 0; o < 32; ++o){
          float qv = dot32(&WST[1024 + o*32], xr);
          XBIG[tid*100 + OUT + o] = leaky(pm[o] + qv + p.t[5][o]);
        }
      }
      __syncthreads();
    }
  }

  // ---- W6 (512x96) via MFMA bf16x3 split, max over n in-register -> g ----
  // mt loops FULLY UNROLLED: gmax[] must only see compile-time indices (rule #20)
  {
    float4v gmax[8];
    #pragma unroll
    for(int i = 0; i < 8; ++i){ gmax[i][0] = -3.4e38f; gmax[i][1] = -3.4e38f; gmax[i][2] = -3.4e38f; gmax[i][3] = -3.4e38f; }
    #pragma unroll 1
    for(int nt = 0; nt < 7; ++nt){
      int row = nt*16 + l15; if(row > 99) row = 99;   // dup row: harmless under max
      short8 Bh[3], Bl[3];
      #pragma unroll
      for(int g = 0; g < 3; ++g) buildB(&XBIG[row*100 + g*32 + quad*8], &Bh[g], &Bl[g]);
      #pragma unroll
      for(int mt = 0; mt < 8; ++mt){
        int orow = (wv*8 + mt)*16 + l15;
        const unsigned short* ar = w6b + orow*288 + quad*8;
        float4v d = {0.f, 0.f, 0.f, 0.f};
        #pragma unroll
        for(int kb = 0; kb < 9; ++kb){
          short8 a = *(const short8*)(ar + kb*32);
          short8 bb = (kb < 3) ? Bh[kb] : ((kb < 6) ? Bl[kb-3] : Bh[kb-6]);
          d = __builtin_amdgcn_mfma_f32_16x16x32_bf16(a, bb, d, 0, 0, 0);
        }
        #pragma unroll
        for(int r = 0; r < 4; ++r) gmax[mt][r] = fmaxf(gmax[mt][r], d[r]);
      }
    }
    #pragma unroll
    for(int mt = 0; mt < 8; ++mt){
      float4v m = gmax[mt];
      #pragma unroll
      for(int bit = 1; bit < 16; bit <<= 1){
        m[0] = fmaxf(m[0], __shfl_xor(m[0], bit, 64));
        m[1] = fmaxf(m[1], __shfl_xor(m[1], bit, 64));
        m[2] = fmaxf(m[2], __shfl_xor(m[2], bit, 64));
        m[3] = fmaxf(m[3], __shfl_xor(m[3], bit, 64));
      }
      if(l15 == 0){
        #pragma unroll
        for(int r = 0; r < 4; ++r){
          int o = (wv*8 + mt)*16 + quad*4 + r;
          WST[o] = leaky(m[r] + p.t[6][o]);   // g[512] at WST[0..512)
        }
      }
    }
  }
  __syncthreads();

  // ---- Rg[o] = W7g . g (vector fp32) ----
  if(tid < 128){
    const float* wr = &ws[W7G_OFF + tid*512];
    float a0 = 0.f, a1 = 0.f, a2 = 0.f, a3 = 0.f;
    #pragma unroll 4
    for(int c4 = 0; c4 < 128; ++c4){
      float4v w = *(const float4v*)&wr[c4*4];
      float4v g = *(const float4v*)&WST[c4*4];
      a0 = fmaf(w.x, g.x, a0); a1 = fmaf(w.y, g.y, a1);
      a2 = fmaf(w.z, g.z, a2); a3 = fmaf(w.w, g.w, a3);
    }
    WST[512 + tid] = (a0+a1)+(a2+a3);
  }
  __syncthreads();

  // ---- tail: per 16-point chunk: W7(96-part) MFMA -> h2; W8 MFMA; W9 reduce ----
  float* H2 = PREG;   // [16][132]
  #pragma unroll 1
  for(int nc = 0; nc < 7; ++nc){
    int n0 = nc*16;
    int row = n0 + l15; if(row > 99) row = 99;
    short8 Bh[3], Bl[3];
    #pragma unroll
    for(int g = 0; g < 3; ++g) buildB(&XBIG[row*100 + g*32 + quad*8], &Bh[g], &Bl[g]);
    #pragma unroll 1
    for(int mm = 0; mm < 2; ++mm){
      int Mt = wv*2 + mm;
      const unsigned short* ar = w796 + (Mt*16 + l15)*288 + quad*8;
      float4v d = {0.f, 0.f, 0.f, 0.f};
      #pragma unroll
      for(int kb = 0; kb < 9; ++kb){
        short8 a = *(const short8*)(ar + kb*32);
        short8 bb = (kb < 3) ? Bh[kb] : ((kb < 6) ? Bl[kb-3] : Bh[kb-6]);
        d = __builtin_amdgcn_mfma_f32_16x16x32_bf16(a, bb, d, 0, 0, 0);
      }
      float4v y;
      #pragma unroll
      for(int r = 0; r < 4; ++r){
        int ch = Mt*16 + quad*4 + r;
        y[r] = leaky(d[r] + WST[512 + ch] + p.t[7][ch]);
      }
      *(float4v*)&H2[l15*132 + Mt*16 + quad*4] = y;
    }
    __syncthreads();
    if(wv < 2){
      short8 Ch[4], Cl[4];
      #pragma unroll
      for(int g = 0; g < 4; ++g) buildB(&H2[l15*132 + g*32 + quad*8], &Ch[g], &Cl[g]);
      const unsigned short* ar = w8b + (wv*16 + l15)*384 + quad*8;
      float4v d = {0.f, 0.f, 0.f, 0.f};
      #pragma unroll
      for(int kb = 0; kb < 12; ++kb){
        short8 a = *(const short8*)(ar + kb*32);
        short8 bb = (kb < 4) ? Ch[kb] : ((kb < 8) ? Cl[kb-4] : Ch[kb-8]);
        d = __builtin_amdgcn_mfma_f32_16x16x32_bf16(a, bb, d, 0, 0, 0);
      }
      float partial = 0.f;
      #pragma unroll
      for(int r = 0; r < 4; ++r){
        int o = wv*16 + quad*4 + r;
        float h3 = leaky(d[r] + p.t[8][o]);
        partial = fmaf(p.W9[o], h3, partial);
      }
      partial += __shfl_xor(partial, 16, 64);
      partial += __shfl_xor(partial, 32, 64);
      if(lane < 16) TMP[wv*16 + lane] = partial;
    }
    __syncthreads();
    if(tid < 16 && (n0 + tid) < NPT)
      p.out[(size_t)b*NPT + n0 + tid] = TMP[tid] + TMP[16 + tid];
    __syncthreads();
  }
}

extern "C" void kernel_launch(void* const* d_in, const int* in_sizes, int n_in,
                              void* d_out, int out_size, void* d_ws, size_t ws_size,
                              hipStream_t stream) {
  (void)n_in; (void)out_size; (void)ws_size;
  PrepP pp;
  for(int i = 0; i < 9; ++i) pp.W[i] = (const float*)d_in[1 + i];
  for(int i = 0; i < 9; ++i) pp.s[i] = (const float*)d_in[11 + 2*i];
  pp.ws = (float*)d_ws;
  prep_kernel<<<256, 256, 0, stream>>>(pp);

  MainP mp;
  mp.obs = (const float*)d_in[0];
  mp.W9  = (const float*)d_in[10];
  for(int i = 0; i < 9; ++i) mp.t[i] = (const float*)d_in[12 + 2*i];
  mp.ws  = (const float*)d_ws;
  mp.out = (float*)d_out;
  const int B = in_sizes[0] / 3000;
  dgcnn<<<B, 256, 0, stream>>>(mp);
}

// Round 6
// 675.123 us; speedup vs baseline: 1.1784x; 1.1784x over previous
//
#include <hip/hip_runtime.h>

#define NPT 100
#define KK 10

typedef __attribute__((ext_vector_type(8))) short short8;
typedef __attribute__((ext_vector_type(4))) float float4v;

__device__ __forceinline__ float leaky(float v){ return fmaxf(v, 0.2f*v); }
__device__ __forceinline__ unsigned short bf16r(float x){
  unsigned u = __float_as_uint(x);
  return (unsigned short)((u + 0x7FFFu + ((u>>16)&1u)) >> 16);
}
__device__ __forceinline__ float bf2f(unsigned short h){ return __uint_as_float(((unsigned)h)<<16); }

// d_ws layout. float offsets:
#define WV(w) (1024*(w))        // 9 folded 32x32 fp32 mats: W0f,Wp1,Wq1,W2f,Wp3,Wq3,W4f,Wp5,Wq5
#define W7G_OFF 9216            // W7 g-part folded fp32 [128][512]
// byte offsets:
#define W6B_OFF   299008        // W6 folded bf16 [512][288]  (K-blocks: 0-2 hi,3-5 hi,6-8 lo)
#define W796B_OFF 593920        // W7 96-part folded bf16 [128][288]
#define W8B_OFF   667648        // W8 folded bf16 [32][384]   (0-3 hi,4-7 hi,8-11 lo)

struct PrepP {
  const float* W[9];
  const float* s[9];
  float* ws;
};

__global__ __launch_bounds__(256) void prep_kernel(PrepP p){
  int gid = blockIdx.x*256 + threadIdx.x;
  int gs = gridDim.x*256;
  float* ws = p.ws;
  unsigned short* w6b  = (unsigned short*)((char*)ws + W6B_OFF);
  unsigned short* w796 = (unsigned short*)((char*)ws + W796B_OFF);
  unsigned short* w8b  = (unsigned short*)((char*)ws + W8B_OFF);
  // seg0: 9 folded vector mats [32][32]
  for(int i = gid; i < 9216; i += gs){
    int w = i >> 10, r = i & 1023, o = r >> 5, c = r & 31;
    float v = 0.f;
    switch(w){
      case 0: v = (c < 30) ? p.s[0][o]*p.W[0][o*30 + c] : 0.f; break;
      case 1: v = p.s[1][o]*p.W[1][o*64 + c]; break;
      case 2: v = p.s[1][o]*(p.W[1][o*64 + 32 + c] - p.W[1][o*64 + c]); break;
      case 3: v = p.s[2][o]*p.W[2][o*32 + c]; break;
      case 4: v = p.s[3][o]*p.W[3][o*64 + c]; break;
      case 5: v = p.s[3][o]*(p.W[3][o*64 + 32 + c] - p.W[3][o*64 + c]); break;
      case 6: v = p.s[4][o]*p.W[4][o*32 + c]; break;
      case 7: v = p.s[5][o]*p.W[5][o*64 + c]; break;
      case 8: v = p.s[5][o]*(p.W[5][o*64 + 32 + c] - p.W[5][o*64 + c]); break;
    }
    ws[i] = v;
  }
  // seg1: W7 g-part fp32 folded [128][512]
  for(int i = gid; i < 65536; i += gs){
    int o = i >> 9, c = i & 511;
    ws[W7G_OFF + i] = p.s[7][o]*p.W[7][o*608 + c];
  }
  // seg2: W6 bf16 [512][288]
  for(int i = gid; i < 147456; i += gs){
    int o = i/288, cc = i - o*288, kb = cc >> 5, k = cc & 31;
    int sc = (kb % 3)*32 + k;
    float w = p.s[6][o]*p.W[6][o*96 + sc];
    unsigned short h = bf16r(w);
    w6b[i] = (kb < 6) ? h : bf16r(w - bf2f(h));
  }
  // seg3: W7 96-part bf16 [128][288]
  for(int i = gid; i < 36864; i += gs){
    int o = i/288, cc = i - o*288, kb = cc >> 5, k = cc & 31;
    int sc = 512 + (kb % 3)*32 + k;
    float w = p.s[7][o]*p.W[7][o*608 + sc];
    unsigned short h = bf16r(w);
    w796[i] = (kb < 6) ? h : bf16r(w - bf2f(h));
  }
  // seg4: W8 bf16 [32][384]
  for(int i = gid; i < 12288; i += gs){
    int o = i/384, cc = i - o*384, kb = cc >> 5, k = cc & 31;
    int sc = (kb & 3)*32 + k;
    float w = p.s[8][o]*p.W[8][o*128 + sc];
    unsigned short h = bf16r(w);
    w8b[i] = (kb < 8) ? h : bf16r(w - bf2f(h));
  }
}

__device__ __forceinline__ void load32(const float* src, float* xr){
  #pragma unroll
  for(int q = 0; q < 8; ++q){
    float4v v = *(const float4v*)&src[q*4];
    xr[q*4+0] = v.x; xr[q*4+1] = v.y; xr[q*4+2] = v.z; xr[q*4+3] = v.w;
  }
}
__device__ __forceinline__ float dot32(const float* wrow, const float* xr){
  float a0 = 0.f, a1 = 0.f, a2 = 0.f, a3 = 0.f;
  #pragma unroll
  for(int q = 0; q < 8; ++q){
    float4v w = *(const float4v*)&wrow[q*4];
    a0 = fmaf(w.x, xr[q*4+0], a0);
    a1 = fmaf(w.y, xr[q*4+1], a1);
    a2 = fmaf(w.z, xr[q*4+2], a2);
    a3 = fmaf(w.w, xr[q*4+3], a3);
  }
  return (a0+a1)+(a2+a3);
}
// build hi/lo bf16 fragments (8 elems) from 8 consecutive fp32
__device__ __forceinline__ void buildB(const float* src, short8* bh, short8* bl){
  float4v v0 = *(const float4v*)&src[0];
  float4v v1 = *(const float4v*)&src[4];
  float xv[8] = {v0.x, v0.y, v0.z, v0.w, v1.x, v1.y, v1.z, v1.w};
  short8 h, l;
  #pragma unroll
  for(int j = 0; j < 8; ++j){
    unsigned short hh = bf16r(xv[j]);
    h[j] = (short)hh;
    l[j] = (short)bf16r(xv[j] - bf2f(hh));
  }
  *bh = h; *bl = l;
}

// conv2 k-chunk of 2: E in regs, weights broadcast from LDS
__device__ __forceinline__ void conv2_chunk2(int n, int k0, int ob,
    const unsigned char* IDXB, const float* PREG, const float* qt,
    const float* WST, float* acc){
  float e0[32], e1[32];
  const int j0 = IDXB[n*KK + k0];
  const int j1 = IDXB[n*KK + k0 + 1];
  #pragma unroll
  for(int q = 0; q < 8; ++q){
    float4v p0 = *(const float4v*)&PREG[j0*36 + q*4];
    float4v p1 = *(const float4v*)&PREG[j1*36 + q*4];
    e0[q*4+0] = leaky(p0.x + qt[q*4+0]);
    e0[q*4+1] = leaky(p0.y + qt[q*4+1]);
    e0[q*4+2] = leaky(p0.z + qt[q*4+2]);
    e0[q*4+3] = leaky(p0.w + qt[q*4+3]);
    e1[q*4+0] = leaky(p1.x + qt[q*4+0]);
    e1[q*4+1] = leaky(p1.y + qt[q*4+1]);
    e1[q*4+2] = leaky(p1.z + qt[q*4+2]);
    e1[q*4+3] = leaky(p1.w + qt[q*4+3]);
  }
  #pragma unroll
  for(int o = 0; o < 8; ++o){
    float d0a = 0.f, d0b = 0.f, d1a = 0.f, d1b = 0.f;
    #pragma unroll
    for(int q = 0; q < 8; ++q){
      float4v w = *(const float4v*)&WST[(ob + o)*32 + q*4];
      d0a = fmaf(w.x, e0[q*4+0], d0a); d0b = fmaf(w.y, e0[q*4+1], d0b);
      d0a = fmaf(w.z, e0[q*4+2], d0a); d0b = fmaf(w.w, e0[q*4+3], d0b);
      d1a = fmaf(w.x, e1[q*4+0], d1a); d1b = fmaf(w.y, e1[q*4+1], d1b);
      d1a = fmaf(w.z, e1[q*4+2], d1a); d1b = fmaf(w.w, e1[q*4+3], d1b);
    }
    acc[o] = fmaxf(acc[o], fmaxf(d0a + d0b, d1a + d1b));
  }
}

struct MainP {
  const float* obs;
  const float* W9;
  const float* t[9];
  const float* ws;
  float* out;
};

// 256 threads, 2 blocks/CU (LDS-limited). Verified-best structure.
// DO NOT raise block size to 512 (R1/R2: spills or 1-block residency, ~1.9x dur).
// Compiler is pinned at 128 arch-VGPRs (every build lands exactly 128 and
// spills rather than exceed it — R4 proved forcing promotion backfires).
// Therefore: eliminate local-memory arrays by REDUCING live state, never by
// unrolling into the wall.
//   - W6 phase: M-tiles processed in 2 halves of 4 -> gmax[4] (16 regs) with
//     compile-time indices only. (R3 form: gmax[8] under unroll-1 = local mem,
//     ~229 KB/block scratch. R4 form: gmax[8] full-unroll = pressure spill,
//     WRITE_SIZE 430 MB.)
//   - layer 3: pm as float4v per 4-output group (was pm[32] read with runtime
//     o under unroll-1 = local mem, ~140 KB/block scratch).
__global__ __launch_bounds__(256, 2) void dgcnn(MainP p){
  const int b = blockIdx.x;
  const int tid = threadIdx.x;
  const int lane = tid & 63, wv = tid >> 6;
  const int quad = lane >> 4, l15 = lane & 15;

  // LDS: 40000 + 14400 + 8192 + 400 + 128 + 1000 = 64120 B
  __shared__ __align__(16) float XBIG[10000];  // [100][100]: x1(0-31)|x2(32-63)|x3/x0/Q(64-95)|pad
  __shared__ __align__(16) float PREG[3600];   // obs stage -> P[100][36] -> h2[16][132]
  __shared__ __align__(16) float WST[2048];    // weight stage / g[512]+Rg[128]
  __shared__ __align__(16) float XX[100];
  __shared__ __align__(16) float TMP[32];
  __shared__ unsigned char IDXB[1000];

  const float* ws = p.ws;
  const unsigned short* w6b  = (const unsigned short*)((const char*)ws + W6B_OFF);
  const unsigned short* w796 = (const unsigned short*)((const char*)ws + W796B_OFF);
  const unsigned short* w8b  = (const unsigned short*)((const char*)ws + W8B_OFF);

  // ---- stage obs (zero-padded [100][36]) + W0f ----
  for(int i = tid; i < 3600; i += 256){
    int n = i/36, c = i - n*36;
    PREG[i] = (c < 30) ? p.obs[(size_t)b*3000 + n*30 + c] : 0.f;
  }
  for(int i = tid; i < 1024; i += 256) WST[i] = ws[WV(0) + i];
  __syncthreads();

  // ---- conv0 (vector fp32, folded s0) -> x0 at cols 64-95 ----
  if(tid < NPT){
    float xr[32]; load32(&PREG[tid*36], xr);
    #pragma unroll
    for(int ob = 0; ob < 8; ++ob){
      float4v y;
      #pragma unroll
      for(int oi = 0; oi < 4; ++oi){
        int o = ob*4 + oi;
        y[oi] = leaky(dot32(&WST[o*32], xr) + p.t[0][o]);
      }
      *(float4v*)&XBIG[tid*100 + 64 + ob*4] = y;
    }
  }
  __syncthreads();

  // ---- 3 edge layers ----
  const int XINs[3]  = {64, 0, 32};
  const int QOFFs[3] = {32, 64, 0};
  const int OUTs[3]  = {0, 32, 64};
  const int WPI[3]   = {1, 4, 7};

  for(int L = 0; L < 3; ++L){
    const int XIN = XINs[L], OUT = OUTs[L], QOFF = QOFFs[L];
    // stage Wp, Wq
    for(int i = tid; i < 1024; i += 256){
      WST[i]        = ws[WV(WPI[L])   + i];
      WST[1024 + i] = ws[WV(WPI[L]+1) + i];
    }
    __syncthreads();
    // xx
    if(tid < NPT){
      float xr[32]; load32(&XBIG[tid*100 + XIN], xr);
      float a = 0.f;
      #pragma unroll
      for(int c = 0; c < 32; ++c) a = fmaf(xr[c], xr[c], a);
      XX[tid] = a;
    }
    __syncthreads();
    // knn (waves 0-1) || P,Q GEMMs (waves 2-3)
    if(tid < 128){
      if(tid < NPT){
        const int n = tid;
        float xr[32]; load32(&XBIG[n*100 + XIN], xr);
        const float xxn = XX[n];
        float bv[KK]; int bj[KK];
        #pragma unroll
        for(int k = 0; k < KK; ++k){ bv[k] = -3.4e38f; bj[k] = 0; }
        #pragma unroll 1
        for(int m = 0; m < NPT; ++m){
          const float* xm = &XBIG[m*100 + XIN];
          float a0 = 0.f, a1 = 0.f, a2 = 0.f, a3 = 0.f;
          #pragma unroll
          for(int q = 0; q < 8; ++q){
            float4v v = *(const float4v*)&xm[q*4];
            a0 = fmaf(xr[q*4+0], v.x, a0);
            a1 = fmaf(xr[q*4+1], v.y, a1);
            a2 = fmaf(xr[q*4+2], v.z, a2);
            a3 = fmaf(xr[q*4+3], v.w, a3);
          }
          float d = 2.0f*((a0+a1)+(a2+a3)) - xxn - XX[m];
          if(d > bv[KK-1]){   // strict >: earlier m wins ties (matches lax.top_k)
            float cv = d; int ci = m;
            #pragma unroll
            for(int jj = 0; jj < KK; ++jj){
              bool sw = cv > bv[jj];
              float tv = bv[jj]; int ti = bj[jj];
              bv[jj] = sw ? cv : tv; bj[jj] = sw ? ci : ti;
              cv = sw ? tv : cv;    ci = sw ? ti : ci;
            }
          }
        }
        #pragma unroll
        for(int k = 0; k < KK; ++k) IDXB[n*KK + k] = (unsigned char)bj[k];
      }
    } else {
      int j = tid - 128;
      if(j < NPT){
        float xr[32]; load32(&XBIG[j*100 + XIN], xr);
        #pragma unroll 1
        for(int o = 0; o < 32; ++o) PREG[j*36 + o] = dot32(&WST[o*32], xr);
        if(L < 2){
          #pragma unroll 1
          for(int o = 0; o < 32; ++o) XBIG[j*100 + QOFF + o] = dot32(&WST[1024 + o*32], xr);
        }
      }
    }
    __syncthreads();

    if(L < 2){
      // stage conv weights (folded) + t-biases
      int wci = (L == 0) ? 3 : 6;
      for(int i = tid; i < 1024; i += 256) WST[i] = ws[WV(wci) + i];
      if(tid < 32){
        WST[1024 + tid] = p.t[1 + 2*L][tid];
        WST[1056 + tid] = p.t[2 + 2*L][tid];
      }
      __syncthreads();
      // conv2: thread = (n, o-octet); E regenerated per octet, weights LDS broadcast
      for(int it = tid; it < 400; it += 256){
        int n = it % 100, oct = it / 100, ob = oct*8;
        float qt[32];
        #pragma unroll
        for(int q = 0; q < 8; ++q){
          float4v qv = *(const float4v*)&XBIG[n*100 + QOFF + q*4];
          float4v tv = *(const float4v*)&WST[1024 + q*4];
          qt[q*4+0] = qv.x + tv.x; qt[q*4+1] = qv.y + tv.y;
          qt[q*4+2] = qv.z + tv.z; qt[q*4+3] = qv.w + tv.w;
        }
        float acc[8];
        #pragma unroll
        for(int o = 0; o < 8; ++o) acc[o] = -3.4e38f;
        conv2_chunk2(n, 0, ob, IDXB, PREG, qt, WST, acc);
        conv2_chunk2(n, 2, ob, IDXB, PREG, qt, WST, acc);
        conv2_chunk2(n, 4, ob, IDXB, PREG, qt, WST, acc);
        conv2_chunk2(n, 6, ob, IDXB, PREG, qt, WST, acc);
        conv2_chunk2(n, 8, ob, IDXB, PREG, qt, WST, acc);
        #pragma unroll
        for(int oh = 0; oh < 2; ++oh){
          float4v y;
          #pragma unroll
          for(int oi = 0; oi < 4; ++oi){
            int o = ob + oh*4 + oi;
            y[oi] = leaky(acc[oh*4 + oi] + WST[1056 + o]);
          }
          *(float4v*)&XBIG[n*100 + OUT + ob + oh*4] = y;
        }
      }
      __syncthreads();
    } else {
      // layer 3: x3 = leaky(max_k P[j] + Q + t5), per 4-output group.
      // pm is a float4v with compile-time component access only (rule #20:
      // pm[32] read with runtime o was local memory -> ~140 KB/block scratch).
      if(tid < NPT){
        float xr[32]; load32(&XBIG[tid*100 + XIN], xr);
        #pragma unroll 1
        for(int og = 0; og < 8; ++og){
          float4v pm = {-3.4e38f, -3.4e38f, -3.4e38f, -3.4e38f};
          #pragma unroll 1
          for(int k = 0; k < KK; ++k){
            int j = IDXB[tid*KK + k];
            float4v pv = *(const float4v*)&PREG[j*36 + og*4];
            pm[0] = fmaxf(pm[0], pv.x);
            pm[1] = fmaxf(pm[1], pv.y);
            pm[2] = fmaxf(pm[2], pv.z);
            pm[3] = fmaxf(pm[3], pv.w);
          }
          float4v y;
          #pragma unroll
          for(int oi = 0; oi < 4; ++oi){
            int o = og*4 + oi;
            float qv = dot32(&WST[1024 + o*32], xr);
            y[oi] = leaky(pm[oi] + qv + p.t[5][o]);
          }
          *(float4v*)&XBIG[tid*100 + OUT + og*4] = y;
        }
      }
      __syncthreads();
    }
  }

  // ---- W6 (512x96) via MFMA bf16x3 split, max over n in-register -> g ----
  // 2 halves x 4 M-tiles: gmax[4] (16 VGPRs) with compile-time indices only.
  // Halved live state fits under the 128-VGPR wall (R4: 8-tile unroll spilled).
  // buildB runs 2x (14 vs 7 nt-iterations) — ~1% extra VALU, no scratch.
  #pragma unroll 1
  for(int mh = 0; mh < 2; ++mh){
    float4v gmax[4];
    #pragma unroll
    for(int i = 0; i < 4; ++i){ gmax[i][0] = -3.4e38f; gmax[i][1] = -3.4e38f; gmax[i][2] = -3.4e38f; gmax[i][3] = -3.4e38f; }
    #pragma unroll 1
    for(int nt = 0; nt < 7; ++nt){
      int row = nt*16 + l15; if(row > 99) row = 99;   // dup row: harmless under max
      short8 Bh[3], Bl[3];
      #pragma unroll
      for(int g = 0; g < 3; ++g) buildB(&XBIG[row*100 + g*32 + quad*8], &Bh[g], &Bl[g]);
      #pragma unroll
      for(int mt = 0; mt < 4; ++mt){
        int orow = (wv*8 + mh*4 + mt)*16 + l15;
        const unsigned short* ar = w6b + orow*288 + quad*8;
        float4v d = {0.f, 0.f, 0.f, 0.f};
        #pragma unroll
        for(int kb = 0; kb < 9; ++kb){
          short8 a = *(const short8*)(ar + kb*32);
          short8 bb = (kb < 3) ? Bh[kb] : ((kb < 6) ? Bl[kb-3] : Bh[kb-6]);
          d = __builtin_amdgcn_mfma_f32_16x16x32_bf16(a, bb, d, 0, 0, 0);
        }
        #pragma unroll
        for(int r = 0; r < 4; ++r) gmax[mt][r] = fmaxf(gmax[mt][r], d[r]);
      }
    }
    #pragma unroll
    for(int mt = 0; mt < 4; ++mt){
      float4v m = gmax[mt];
      #pragma unroll
      for(int bit = 1; bit < 16; bit <<= 1){
        m[0] = fmaxf(m[0], __shfl_xor(m[0], bit, 64));
        m[1] = fmaxf(m[1], __shfl_xor(m[1], bit, 64));
        m[2] = fmaxf(m[2], __shfl_xor(m[2], bit, 64));
        m[3] = fmaxf(m[3], __shfl_xor(m[3], bit, 64));
      }
      if(l15 == 0){
        #pragma unroll
        for(int r = 0; r < 4; ++r){
          int o = (wv*8 + mh*4 + mt)*16 + quad*4 + r;
          WST[o] = leaky(m[r] + p.t[6][o]);   // g[512] at WST[0..512)
        }
      }
    }
  }
  __syncthreads();

  // ---- Rg[o] = W7g . g (vector fp32) ----
  if(tid < 128){
    const float* wr = &ws[W7G_OFF + tid*512];
    float a0 = 0.f, a1 = 0.f, a2 = 0.f, a3 = 0.f;
    #pragma unroll 4
    for(int c4 = 0; c4 < 128; ++c4){
      float4v w = *(const float4v*)&wr[c4*4];
      float4v g = *(const float4v*)&WST[c4*4];
      a0 = fmaf(w.x, g.x, a0); a1 = fmaf(w.y, g.y, a1);
      a2 = fmaf(w.z, g.z, a2); a3 = fmaf(w.w, g.w, a3);
    }
    WST[512 + tid] = (a0+a1)+(a2+a3);
  }
  __syncthreads();

  // ---- tail: per 16-point chunk: W7(96-part) MFMA -> h2; W8 MFMA; W9 reduce ----
  float* H2 = PREG;   // [16][132]
  #pragma unroll 1
  for(int nc = 0; nc < 7; ++nc){
    int n0 = nc*16;
    int row = n0 + l15; if(row > 99) row = 99;
    short8 Bh[3], Bl[3];
    #pragma unroll
    for(int g = 0; g < 3; ++g) buildB(&XBIG[row*100 + g*32 + quad*8], &Bh[g], &Bl[g]);
    #pragma unroll 1
    for(int mm = 0; mm < 2; ++mm){
      int Mt = wv*2 + mm;
      const unsigned short* ar = w796 + (Mt*16 + l15)*288 + quad*8;
      float4v d = {0.f, 0.f, 0.f, 0.f};
      #pragma unroll
      for(int kb = 0; kb < 9; ++kb){
        short8 a = *(const short8*)(ar + kb*32);
        short8 bb = (kb < 3) ? Bh[kb] : ((kb < 6) ? Bl[kb-3] : Bh[kb-6]);
        d = __builtin_amdgcn_mfma_f32_16x16x32_bf16(a, bb, d, 0, 0, 0);
      }
      float4v y;
      #pragma unroll
      for(int r = 0; r < 4; ++r){
        int ch = Mt*16 + quad*4 + r;
        y[r] = leaky(d[r] + WST[512 + ch] + p.t[7][ch]);
      }
      *(float4v*)&H2[l15*132 + Mt*16 + quad*4] = y;
    }
    __syncthreads();
    if(wv < 2){
      short8 Ch[4], Cl[4];
      #pragma unroll
      for(int g = 0; g < 4; ++g) buildB(&H2[l15*132 + g*32 + quad*8], &Ch[g], &Cl[g]);
      const unsigned short* ar = w8b + (wv*16 + l15)*384 + quad*8;
      float4v d = {0.f, 0.f, 0.f, 0.f};
      #pragma unroll
      for(int kb = 0; kb < 12; ++kb){
        short8 a = *(const short8*)(ar + kb*32);
        short8 bb = (kb < 4) ? Ch[kb] : ((kb < 8) ? Cl[kb-4] : Ch[kb-8]);
        d = __builtin_amdgcn_mfma_f32_16x16x32_bf16(a, bb, d, 0, 0, 0);
      }
      float partial = 0.f;
      #pragma unroll
      for(int r = 0; r < 4; ++r){
        int o = wv*16 + quad*4 + r;
        float h3 = leaky(d[r] + p.t[8][o]);
        partial = fmaf(p.W9[o], h3, partial);
      }
      partial += __shfl_xor(partial, 16, 64);
      partial += __shfl_xor(partial, 32, 64);
      if(lane < 16) TMP[wv*16 + lane] = partial;
    }
    __syncthreads();
    if(tid < 16 && (n0 + tid) < NPT)
      p.out[(size_t)b*NPT + n0 + tid] = TMP[tid] + TMP[16 + tid];
    __syncthreads();
  }
}

extern "C" void kernel_launch(void* const* d_in, const int* in_sizes, int n_in,
                              void* d_out, int out_size, void* d_ws, size_t ws_size,
                              hipStream_t stream) {
  (void)n_in; (void)out_size; (void)ws_size;
  PrepP pp;
  for(int i = 0; i < 9; ++i) pp.W[i] = (const float*)d_in[1 + i];
  for(int i = 0; i < 9; ++i) pp.s[i] = (const float*)d_in[11 + 2*i];
  pp.ws = (float*)d_ws;
  prep_kernel<<<256, 256, 0, stream>>>(pp);

  MainP mp;
  mp.obs = (const float*)d_in[0];
  mp.W9  = (const float*)d_in[10];
  for(int i = 0; i < 9; ++i) mp.t[i] = (const float*)d_in[12 + 2*i];
  mp.ws  = (const float*)d_ws;
  mp.out = (float*)d_out;
  const int B = in_sizes[0] / 3000;
  dgcnn<<<B, 256, 0, stream>>>(mp);
}